// Round 5
// baseline (341.032 us; speedup 1.0000x reference)
//
#include <hip/hip_runtime.h>
#include <math.h>

typedef __bf16 bf16;
typedef __attribute__((ext_vector_type(8))) __bf16 bf16x8;
typedef __attribute__((ext_vector_type(4))) float f32x4;

// ---------------------------------------------------------------------------
// B=16, L=1024, U=512, H=2. M = 16384. fp32 I/O, bf16 internal.
// R15: fragment-linear attention. gemm_dual<2> emits q16/x2/xT in MFMA-frag-
// linear layouts (1KB per 16x32 frag); attn reads all operands as coalesced
// 1KB L2 loads with NO LDS staging and NO barriers in QK^T (2 barriers/jt for
// the Es handoff only). Es swizzle + lsum reduction carried from R14-verified.
// ---------------------------------------------------------------------------

__device__ __forceinline__ void load_lds16(const bf16* g, bf16* l) {
  __builtin_amdgcn_global_load_lds(
      (const __attribute__((address_space(1))) unsigned int*)(g),
      (__attribute__((address_space(3))) unsigned int*)(l), 16, 0, 0);
}

// ===================== dual-column fused-gating GEMM =======================
// (R0-proven 128x128 tile, 4 waves 2x2, BK=64, granule-XOR swizzle.)
struct DualArgs {
  const bf16* A; const bf16* A2;   // A2 = rows for k>=512 (final); else == A
  const bf16* Bt;
  void* C; const void* xres;       // EPI2: C = x2 frag-linear (B-frag layout)
  const float* bias_t; const float* bias_c;
  int K, ldb;
  const float* aW;                 // EPI 2
  float* s1a; float* s2a;          // EPI 2: atomic partial dots
  bf16* q;                         // EPI 2: q frag-linear (A-frag layout)
  bf16* xT;                        // EPI 2: xT frag-linear (B-frag layout)
};

template<int EPI>  // 0 = highway, 2 = highway + frag-linear outputs, 1 = final
__global__ __launch_bounds__(256, 4)
void gemm_dual(DualArgs g) {
  __shared__ bf16 smem[2 * 128 * 64];      // As | Bs; reused as Ts/Ts2 in EPI2
  bf16* As = smem;
  bf16* Bs = smem + 8192;
  const int tid = threadIdx.x;
  const int bid = blockIdx.x;
  const int xcd = bid & 7;
  const int t = bid >> 3;
  const int bx = t & 7;
  const int r  = t >> 3;
  const int Rx = gridDim.x >> 6;
  const int by = xcd * Rx + r;

  const int wid = tid >> 6, lane = tid & 63;
  const int wm = (wid >> 1) << 6;
  const int wn = (wid & 1) << 6;
  const int lr = lane & 15, lq = lane >> 4;

  f32x4 acc[4][4];
#pragma unroll
  for (int i = 0; i < 4; i++)
#pragma unroll
    for (int j = 0; j < 4; j++) acc[i][j] = f32x4{0.f, 0.f, 0.f, 0.f};

  const int srow8 = (tid >> 3) & 7;
  const int skc   = (tid & 7) ^ srow8;
  const int lswz  = (lr & 7);
  const long long abase = (long long)(by * 128) * 512;

  for (int k0 = 0; k0 < g.K; k0 += 64) {
    const bf16* Ak = (k0 < 512) ? g.A : g.A2;
    const int kk = k0 & 511;
    __syncthreads();
#pragma unroll
    for (int j = 0; j < 4; j++) {
      const int ci = (tid >> 6) * 4 + j;
      const int bn = ci * 8 + srow8;
      load_lds16(Ak + abase + (long long)bn * 512 + kk + skc * 8, As + ci * 512);
      const int grp = bn >> 5, r5 = bn & 31;
      const int grow = ((grp & 1) << 9) + bx * 64 + ((grp >> 1) << 5) + r5;
      load_lds16(g.Bt + (long long)grow * g.ldb + k0 + skc * 8, Bs + ci * 512);
    }
    __syncthreads();
#pragma unroll
    for (int ks = 0; ks < 2; ks++) {
      bf16x8 af[4], bfr[4];
      const int kx = (ks * 4 + lq) ^ lswz;
#pragma unroll
      for (int i = 0; i < 4; i++)
        af[i] = *(const bf16x8*)(&As[(wm + i * 16 + lr) * 64 + kx * 8]);
#pragma unroll
      for (int j = 0; j < 4; j++)
        bfr[j] = *(const bf16x8*)(&Bs[(wn + j * 16 + lr) * 64 + kx * 8]);
#pragma unroll
      for (int i = 0; i < 4; i++)
#pragma unroll
        for (int j = 0; j < 4; j++)
          acc[i][j] = __builtin_amdgcn_mfma_f32_16x16x32_bf16(af[i], bfr[j], acc[i][j], 0, 0, 0);
    }
  }

  const int colb = bx * 64 + (wn >> 1);
  bf16 xn_arr[4][4][2];
#pragma unroll
  for (int i = 0; i < 4; i++) {
#pragma unroll
    for (int v = 0; v < 4; v++) {
      int row = by * 128 + wm + i * 16 + lq * 4 + v;
      float p1s = 0.f, p2s = 0.f;
#pragma unroll
      for (int j = 0; j < 2; j++) {
        int col = colb + j * 16 + lr;
        long long idx = (long long)row * 512 + col;
        float p0 = acc[i][j][v] + g.bias_t[col];
        float p1 = acc[i][j + 2][v] + g.bias_c[col];
        if (EPI == 1) {
          float z = 1.f / (1.f + __expf(-p0));
          float rr = 1.f / (1.f + __expf(-p1));
          float x = (float)((const bf16*)g.xres)[idx];   // bf16 residual
          ((float*)g.C)[idx] = rr * x + z * z;
        } else {
          float tt = fmaxf(p0, 0.f);
          float c = 1.f / (1.f + __expf(-p1));
          float x = (float)((const bf16*)g.xres)[idx];
          bf16 xn = (bf16)(tt * c + x * (1.f - c));
          if (EPI == 0) ((bf16*)g.C)[idx] = xn;
          if (EPI == 2) {
            xn_arr[i][v][j] = xn;
            float xf = (float)xn;
            p1s += xf * g.aW[col];
            p2s += xf * g.aW[512 + col];
          }
        }
      }
      if (EPI == 2) {
        p1s += __shfl_xor(p1s, 1, 64);
        p1s += __shfl_xor(p1s, 2, 64);
        p1s += __shfl_xor(p1s, 4, 64);
        p1s += __shfl_xor(p1s, 8, 64);
        p2s += __shfl_xor(p2s, 1, 64);
        p2s += __shfl_xor(p2s, 2, 64);
        p2s += __shfl_xor(p2s, 4, 64);
        p2s += __shfl_xor(p2s, 8, 64);
        if (lr == 0) {
          atomicAdd(&g.s1a[row], p1s);
          atomicAdd(&g.s2a[row], p2s);
        }
      }
    }
  }

  if (EPI == 2) {
    const int l15 = lane & 15, l4 = lane >> 4;
    const long long bb = (long long)(by >> 3) * 524288;
    // ---- Ts: d-major [cloc=d 64][rloc=j 128] stride 136 -> xTf frags ------
    bf16* Ts = smem;
    __syncthreads();
#pragma unroll
    for (int i = 0; i < 4; i++)
#pragma unroll
      for (int v = 0; v < 4; v++)
#pragma unroll
        for (int j = 0; j < 2; j++) {
          int rloc = wm + i * 16 + lq * 4 + v;
          int cloc = (wn >> 1) + j * 16 + lr;
          Ts[cloc * 136 + rloc] = xn_arr[i][v][j];
        }
    __syncthreads();
    // xTf frag (D=d/16, J=j/32): lane = ((j%32)/8)*16 + d%16, e = j%8
    {
      bf16* xtf = g.xT + bb;
#pragma unroll
      for (int f = 0; f < 4; f++) {
        const int id = wid * 4 + f;
        const int Dl = id >> 2, Jl = id & 3;
        bf16x8 v = *(const bf16x8*)(&Ts[(Dl * 16 + l15) * 136 + Jl * 32 + l4 * 8]);
        const int D = bx * 4 + Dl, J = (by & 7) * 4 + Jl;
        *(bf16x8*)(xtf + ((long long)(D * 32 + J) * 64 + lane) * 8) = v;
      }
    }
    __syncthreads();
    // ---- Ts2: row-major [rloc 128][cloc 64] stride 72 -> q/x2 frags -------
    bf16* Ts2 = smem;
#pragma unroll
    for (int i = 0; i < 4; i++)
#pragma unroll
      for (int v = 0; v < 4; v++)
#pragma unroll
        for (int j = 0; j < 2; j++) {
          int rloc = wm + i * 16 + lq * 4 + v;
          int cloc = (wn >> 1) + j * 16 + lr;
          Ts2[rloc * 72 + cloc] = xn_arr[i][v][j];
        }
    __syncthreads();
    // q frag (A-layout) + x2 frag (B-layout): both [16 rows x 32 cols],
    // lane = ((col%32)/8)*16 + row%16, e = col%8. Same source read.
    {
      bf16* qf = g.q + bb;
      bf16* xf = (bf16*)g.C + bb;
#pragma unroll
      for (int f = 0; f < 4; f++) {
        const int id = wid * 4 + f;
        const int Rl = id >> 1, Pl = id & 1;
        bf16x8 v = *(const bf16x8*)(&Ts2[(Rl * 16 + l15) * 72 + Pl * 32 + l4 * 8]);
        const long long o = ((long long)(((by & 7) * 8 + Rl) * 16 + (bx * 2 + Pl)) * 64 + lane) * 8;
        *(bf16x8*)(xf + o) = v;
        const float* aw = g.aW + 1024 + bx * 64 + Pl * 32 + l4 * 8;
        f32x4 w0 = *(const f32x4*)aw;
        f32x4 w1 = *(const f32x4*)(aw + 4);
        bf16x8 qv;
#pragma unroll
        for (int k = 0; k < 4; k++) qv[k] = (bf16)((float)v[k] * w0[k]);
#pragma unroll
        for (int k = 0; k < 4; k++) qv[4 + k] = (bf16)((float)v[4 + k] * w1[k]);
        *(bf16x8*)(qf + o) = qv;
      }
    }
  }
}

// ======================= fused flash scores + PV ===========================
// 256 blocks (16 batch x 16 Q-tiles of 64 rows), 512 thr, 8 waves (wr2 x wc4).
// All operands frag-linear in global (batch pinned to one XCD's L2 by the
// gr mapping). QK^T: zero barriers, 48 coalesced 1KB loads + 32 MFMA per
// wave per jt. Es (swizzled, R14-verified) is the only LDS handoff.
struct AttnArgs {
  const bf16* Qf;    // q frag-linear   [b][R=row/16][P=k/32][64][8]
  const bf16* Xf;    // x2 frag-linear  [b][J2=j/16][Pd=d/32][64][8]
  const bf16* XTf;   // xT frag-linear  [b][D=d/16][J=j/32][64][8]
  bf16* O;           // att16 [16][1024][512] row-major
  const float* s1; const float* s2; const float* abp;
};

__global__ __launch_bounds__(512, 2)
void attn_fused(AttnArgs g) {
  __shared__ __align__(16) bf16 smem[33280];   // Es [0,8192) ; epilogue Ts
  __shared__ float lsum_sh[4][64];
  const int tid = threadIdx.x;
  const int bid = blockIdx.x;
  const int gr = (bid & 7) * 32 + (bid >> 3);   // batch pinned per XCD
  const int bz = gr >> 4, qt = gr & 15;
  const int wid = tid >> 6, lane = tid & 63;
  const int wr = wid >> 2, wc = wid & 3;
  const int lr = lane & 15, lq = lane >> 4;

  const bf16* Qf  = g.Qf  + (long long)bz * 524288;
  const bf16* Xf  = g.Xf  + (long long)bz * 524288;
  const bf16* XTf = g.XTf + (long long)bz * 524288;

  float s1r[2][4];
#pragma unroll
  for (int i = 0; i < 2; i++)
#pragma unroll
    for (int v = 0; v < 4; v++)
      s1r[i][v] = g.s1[bz * 1024 + qt * 64 + wr * 32 + i * 16 + lq * 4 + v] + g.abp[0];

  f32x4 acc_o[2][8];
  float lsum[2][4];
#pragma unroll
  for (int i = 0; i < 2; i++) {
#pragma unroll
    for (int jd = 0; jd < 8; jd++) acc_o[i][jd] = f32x4{0.f, 0.f, 0.f, 0.f};
#pragma unroll
    for (int v = 0; v < 4; v++) lsum[i][v] = 0.f;
  }

  for (int jt = 0; jt < 8; jt++) {
    // -------- QK^T over K=512: frag-linear loads, no barriers --------
    f32x4 acc_s[2][2];
#pragma unroll
    for (int i = 0; i < 2; i++)
#pragma unroll
      for (int jjf = 0; jjf < 2; jjf++) acc_s[i][jjf] = f32x4{0.f, 0.f, 0.f, 0.f};

#pragma unroll
    for (int p = 0; p < 8; p++) {
#pragma unroll
      for (int ks = 0; ks < 2; ks++) {
        const int P = p * 2 + ks;
        bf16x8 aq0 = *(const bf16x8*)(Qf + (((qt * 4 + wr * 2 + 0) * 16 + P) * 64 + lane) * 8);
        bf16x8 aq1 = *(const bf16x8*)(Qf + (((qt * 4 + wr * 2 + 1) * 16 + P) * 64 + lane) * 8);
        bf16x8 b0  = *(const bf16x8*)(Xf + (((jt * 8 + wc * 2 + 0) * 16 + P) * 64 + lane) * 8);
        bf16x8 b1  = *(const bf16x8*)(Xf + (((jt * 8 + wc * 2 + 1) * 16 + P) * 64 + lane) * 8);
        acc_s[0][0] = __builtin_amdgcn_mfma_f32_16x16x32_bf16(aq0, b0, acc_s[0][0], 0, 0, 0);
        acc_s[0][1] = __builtin_amdgcn_mfma_f32_16x16x32_bf16(aq0, b1, acc_s[0][1], 0, 0, 0);
        acc_s[1][0] = __builtin_amdgcn_mfma_f32_16x16x32_bf16(aq1, b0, acc_s[1][0], 0, 0, 0);
        acc_s[1][1] = __builtin_amdgcn_mfma_f32_16x16x32_bf16(aq1, b1, acc_s[1][1], 0, 0, 0);
      }
    }

    // -------- E = exp(clamp(relu(S + s1 + s2 + ab))) -> swizzled Es --------
    if (jt) __syncthreads();     // all waves done PV-reading Es(jt-1)
    float s2v[2];
#pragma unroll
    for (int jjf = 0; jjf < 2; jjf++)
      s2v[jjf] = g.s2[bz * 1024 + jt * 128 + wc * 32 + jjf * 16 + lr];
#pragma unroll
    for (int i = 0; i < 2; i++) {
#pragma unroll
      for (int v = 0; v < 4; v++) {
        const int rl = wr * 32 + i * 16 + lq * 4 + v;
        float ps = 0.f;
#pragma unroll
        for (int jjf = 0; jjf < 2; jjf++) {
          const int jl = wc * 32 + jjf * 16 + lr;
          float val = acc_s[i][jjf][v] + s1r[i][v] + s2v[jjf];
          val = fminf(fmaxf(val, 0.f), 60.f);
          val = __expf(val);
          bf16 eb = (bf16)val;
          ps += (float)eb;
          smem[(jl >> 6) * 4096 + rl * 64 + (((jl >> 3) & 7) ^ (rl & 7)) * 8 + (jl & 7)] = eb;
        }
        ps += __shfl_xor(ps, 1, 64);
        ps += __shfl_xor(ps, 2, 64);
        ps += __shfl_xor(ps, 4, 64);
        ps += __shfl_xor(ps, 8, 64);
        lsum[i][v] += ps;
      }
    }
    __syncthreads();   // Es visible to all waves

    // -------- PV: acc_o += E(64x128) @ V; B frags coalesced from XTf -------
#pragma unroll
    for (int kq = 0; kq < 4; kq++) {
      bf16x8 aE[2];
#pragma unroll
      for (int i = 0; i < 2; i++) {
        const int row = wr * 32 + i * 16 + lr;
        aE[i] = *(const bf16x8*)(&smem[(kq >> 1) * 4096 + row * 64 + ((((kq & 1) * 4 + lq) ^ (row & 7)) * 8)]);
      }
#pragma unroll
      for (int jd = 0; jd < 8; jd++) {
        bf16x8 bv = *(const bf16x8*)(XTf + (((wc * 8 + jd) * 32 + jt * 4 + kq) * 64 + lane) * 8);
        acc_o[0][jd] = __builtin_amdgcn_mfma_f32_16x16x32_bf16(aE[0], bv, acc_o[0][jd], 0, 0, 0);
        acc_o[1][jd] = __builtin_amdgcn_mfma_f32_16x16x32_bf16(aE[1], bv, acc_o[1][jd], 0, 0, 0);
      }
    }
  }

  // ------- cross-wave lsum reduction (4 wc waves share each row) ----------
  if (lr == 0) {
#pragma unroll
    for (int i = 0; i < 2; i++)
#pragma unroll
      for (int v = 0; v < 4; v++)
        lsum_sh[wc][wr * 32 + i * 16 + lq * 4 + v] = lsum[i][v];
  }
  __syncthreads();

  float rinv[2][4];
#pragma unroll
  for (int i = 0; i < 2; i++)
#pragma unroll
    for (int v = 0; v < 4; v++) {
      const int rl = wr * 32 + i * 16 + lq * 4 + v;
      rinv[i][v] = 1.f / (lsum_sh[0][rl] + lsum_sh[1][rl] + lsum_sh[2][rl] + lsum_sh[3][rl]);
    }

  // ---------------- epilogue: att = acc_o * rinv via Ts restage -----------
  bf16* Ts = smem;                 // 64 x 520
#pragma unroll
  for (int i = 0; i < 2; i++)
#pragma unroll
    for (int jd = 0; jd < 8; jd++)
#pragma unroll
      for (int v = 0; v < 4; v++) {
        const int rl = wr * 32 + i * 16 + lq * 4 + v;
        const int d = wc * 128 + jd * 16 + lr;
        Ts[rl * 520 + d] = (bf16)(acc_o[i][jd][v] * rinv[i][v]);
      }
  __syncthreads();
  bf16* Og = g.O + (long long)bz * 524288 + (long long)(qt * 64) * 512;
  {
    const int row = tid >> 3;
    const int c8 = (tid & 7) * 8;
#pragma unroll
    for (int it = 0; it < 8; it++) {
      const int col = c8 + it * 64;
      *(bf16x8*)(Og + (long long)row * 512 + col) = *(const bf16x8*)(&Ts[row * 520 + col]);
    }
  }
}

// ============================ prep kernel ==================================
__device__ __forceinline__ void tile_transpose(const float* src, int sld,
                                               bf16* dst, int dld,
                                               int k0, int n0, int tid) {
  __shared__ float tile[64][65];
  const int rr = tid >> 4, c4 = (tid & 15) * 4;
#pragma unroll
  for (int it = 0; it < 4; it++) {
    int r = rr + it * 16;
    f32x4 v = *(const f32x4*)(src + (long long)(k0 + r) * sld + n0 + c4);
    tile[r][c4] = v[0]; tile[r][c4 + 1] = v[1];
    tile[r][c4 + 2] = v[2]; tile[r][c4 + 3] = v[3];
  }
  __syncthreads();
  const int nl = tid >> 2, kb = (tid & 3) * 16;
  bf16x8 o0, o1;
#pragma unroll
  for (int kk = 0; kk < 8; kk++) o0[kk] = (bf16)tile[kb + kk][nl];
#pragma unroll
  for (int kk = 0; kk < 8; kk++) o1[kk] = (bf16)tile[kb + 8 + kk][nl];
  bf16* d = dst + (long long)(n0 + nl) * dld + k0 + kb;
  *(bf16x8*)d = o0;
  *(bf16x8*)(d + 8) = o1;
}

__global__ void prep(const float* tW, const float* tb, const float* cW, const float* cb,
                     const float* frW, const float* frb, const float* ffW, const float* ffb,
                     const float* inp, bf16* xb0,
                     bf16* w1T, bf16* w2T, float* bias1, float* bias2, float* sred) {
  const int bid = blockIdx.x, tid = threadIdx.x;
  if (bid < 256) {
    const int quad = bid >> 6, tile = bid & 63;
    const int l = quad >> 1, half = quad & 1;
    const float* src = (half ? cW : tW) + l * 262144;
    bf16* dst = w1T + l * 524288 + half * 262144;
    tile_transpose(src, 512, dst, 512, (tile >> 3) * 64, (tile & 7) * 64, tid);
  } else if (bid < 512) {
    const int j = bid - 256;
    const int half = j >> 7, tile = j & 127;
    const float* src = half ? frW : ffW;
    bf16* dst = w2T + half * 524288;
    tile_transpose(src, 512, dst, 1024, (tile >> 3) * 64, (tile & 7) * 64, tid);
  } else if (bid < 4608) {
    long long i8 = (((long long)(bid - 512)) * 256 + tid) * 8;
    bf16x8 o;
#pragma unroll
    for (int k = 0; k < 8; k++) o[k] = (bf16)inp[i8 + k];
    *(bf16x8*)(xb0 + i8) = o;
  } else {
    for (int j = tid; j < 3072; j += 256) {
      if (j < 2048) {
        int l = j >> 10, n = j & 1023;
        bias1[j] = (n < 512) ? tb[l * 512 + n] : cb[l * 512 + (n - 512)];
      } else {
        int n = j - 2048;
        bias2[n] = (n < 512) ? ffb[n] : frb[n - 512];
      }
    }
    for (int j = tid; j < 12288; j += 256)
      *(f32x4*)(sred + j * 4) = f32x4{0.f, 0.f, 0.f, 0.f};
  }
}

extern "C" void kernel_launch(void* const* d_in, const int* in_sizes, int n_in,
                              void* d_out, int out_size, void* d_ws, size_t ws_size,
                              hipStream_t stream) {
  const float* inp = (const float*)d_in[0];
  const float* tW  = (const float*)d_in[1];
  const float* tb  = (const float*)d_in[2];
  const float* cW  = (const float*)d_in[3];
  const float* cb  = (const float*)d_in[4];
  const float* aW  = (const float*)d_in[5];
  const float* ab  = (const float*)d_in[6];
  const float* frW = (const float*)d_in[7];
  const float* frb = (const float*)d_in[8];
  const float* ffW = (const float*)d_in[9];
  const float* ffb = (const float*)d_in[10];
  float* out = (float*)d_out;

  char* p = (char*)d_ws;
  auto alloc = [&](size_t bytes) { char* r = p; p += (bytes + 255) & ~size_t(255); return r; };
  bf16* xb0   = (bf16*) alloc(16777216);
  bf16* x1    = (bf16*) alloc(16777216);
  bf16* x2f   = (bf16*) alloc(16777216);   // x2 B-frag-linear
  bf16* q16f  = (bf16*) alloc(16777216);   // q A-frag-linear
  bf16* xTf   = (bf16*) alloc(16777216);   // xT B-frag-linear
  bf16* att16 = (bf16*) alloc(16777216);
  float* sred = (float*)alloc(196608);     // s1 | s2 | (spare)
  bf16* w1T   = (bf16*) alloc(2097152);
  bf16* w2T   = (bf16*) alloc(2097152);
  float* bias1= (float*)alloc(8192);
  float* bias2= (float*)alloc(4096);
  float* s1 = sred, *s2 = sred + 16384;

  prep<<<4609, 256, 0, stream>>>(
      tW, tb, cW, cb, frW, frb, ffW, ffb, inp, xb0, w1T, w2T, bias1, bias2, sred);

  {  // highway 1
    DualArgs g{};
    g.A = xb0; g.A2 = xb0; g.Bt = w1T;
    g.C = x1; g.xres = xb0;
    g.bias_t = bias1; g.bias_c = bias1 + 512;
    g.K = 512; g.ldb = 512;
    gemm_dual<0><<<1024, 256, 0, stream>>>(g);
  }
  {  // highway 2 + fused s1/s2 + frag-linear q/x2/xT outputs
    DualArgs g{};
    g.A = x1; g.A2 = x1; g.Bt = w1T + 524288;
    g.C = x2f; g.xres = x1;
    g.bias_t = bias1 + 1024; g.bias_c = bias1 + 1536;
    g.K = 512; g.ldb = 512;
    g.aW = aW; g.s1a = s1; g.s2a = s2; g.q = q16f; g.xT = xTf;
    gemm_dual<2><<<1024, 256, 0, stream>>>(g);
  }
  {  // fused flash: att = softmax-ish(QK^T + s1 + s2 + ab) @ x2
    AttnArgs g{};
    g.Qf = q16f; g.Xf = x2f; g.XTf = xTf; g.O = att16;
    g.s1 = s1; g.s2 = s2; g.abp = ab;
    attn_fused<<<256, 512, 0, stream>>>(g);
  }
  {  // final: out = r*x + z*z, z/r = sigmoid([xb0|att] @ [ffW|frW] + b)
    DualArgs g{};
    g.A = xb0; g.A2 = att16; g.Bt = w2T;
    g.C = out; g.xres = xb0;               // bf16 residual
    g.bias_t = bias2; g.bias_c = bias2 + 512;
    g.K = 1024; g.ldb = 1024;
    gemm_dual<1><<<1024, 256, 0, stream>>>(g);
  }
}